// Round 1
// baseline (691.241 us; speedup 1.0000x reference)
//
#include <hip/hip_runtime.h>

#define NN 10000
#define NE 640000
#define D  128
#define SLOPE 0.22916666666666666f   // 11/48

typedef float  f32x4  __attribute__((ext_vector_type(4)));
typedef short  bf16x8 __attribute__((ext_vector_type(8)));

static __device__ __forceinline__ unsigned short f2bf(float f) {
    // round-to-nearest-even fp32 -> bf16 (inputs are finite randn; NaN path not needed)
    unsigned u = __builtin_bit_cast(unsigned, f);
    u += 0x7fffu + ((u >> 16) & 1u);
    return (unsigned short)(u >> 16);
}

// ---------------------------------------------------------------- W_edge -> bf16
__global__ void wconv_kernel(const float* __restrict__ W, unsigned short* __restrict__ Wb) {
    int i = blockIdx.x * 256 + threadIdx.x;       // 16384 = 128h * 128k
    int h = i >> 7, k = i & 127;
    Wb[i] = f2bf(W[h * 256 + 128 + k]);           // W[:,128:] row-major [h][k]
}

// ---------------------------------------------------------------- proj_nodes (fp32)
// proj[n][h] = sum_k node_h[n][k] * W[h][k]  (W_src = W[:, :128])
__global__ __launch_bounds__(256) void proj_kernel(
    const float* __restrict__ node_h, const float* __restrict__ W,
    float* __restrict__ proj) {
    __shared__ float sW[64 * 128];   // transposed k-half: sW[kl*128 + h]
    __shared__ float sN[8 * 128];    // 8 node rows
    int t = threadIdx.x;
    int n0 = blockIdx.x * 8;
    for (int i = t; i < 8 * 128; i += 256) sN[i] = node_h[(size_t)n0 * 128 + i];

    int h = t & 127, half = t >> 7;  // 2 halves x 4 nodes each
    float acc[4] = {0.f, 0.f, 0.f, 0.f};
    for (int kh = 0; kh < 2; ++kh) {
        __syncthreads();             // protect sW across iterations; covers sN on iter 0
        {   // load k-half of W_src transposed: thread -> h2=t>>1, 32 k's
            int h2 = t >> 1, kl0 = (t & 1) * 32;
            #pragma unroll
            for (int j = 0; j < 32; j += 4) {
                float4 w = *(const float4*)&W[h2 * 256 + kh * 64 + kl0 + j];
                sW[(kl0 + j + 0) * 128 + h2] = w.x;
                sW[(kl0 + j + 1) * 128 + h2] = w.y;
                sW[(kl0 + j + 2) * 128 + h2] = w.z;
                sW[(kl0 + j + 3) * 128 + h2] = w.w;
            }
        }
        __syncthreads();
        for (int kl = 0; kl < 64; ++kl) {
            float w = sW[kl * 128 + h];           // 2-way bank alias: free
            int k = kh * 64 + kl;
            #pragma unroll
            for (int i = 0; i < 4; ++i)
                acc[i] += w * sN[(half * 4 + i) * 128 + k];   // broadcast
        }
    }
    #pragma unroll
    for (int i = 0; i < 4; ++i)
        proj[(size_t)(n0 + half * 4 + i) * 128 + h] = acc[i];
}

// ---------------------------------------------------------------- fused edge GEMM + scatter
#define LDW 136   // padded LDS row (shorts): 272B -> b128 reads 2-way alias only

__global__ __launch_bounds__(256) void edge_kernel(
    const float* __restrict__ edge_h, const float* __restrict__ nrm,
    const int* __restrict__ src, const int* __restrict__ dst,
    const unsigned short* __restrict__ Wb, const float* __restrict__ proj,
    float* __restrict__ out) {
    __shared__ unsigned short sW[128 * LDW];   // W_edge bf16, [h][k] padded
    __shared__ unsigned short sA[64 * LDW];    // edge tile bf16, [e][k] padded
    __shared__ int   sSrc[64];
    __shared__ int   sDst[64];
    __shared__ float sNorm[64];

    int t  = threadIdx.x;
    int e0 = blockIdx.x * 64;

    {   // stage W (bf16, from ws) into padded LDS
        int h = t >> 1, k0 = (t & 1) * 64;
        #pragma unroll
        for (int j = 0; j < 64; j += 8) {
            uint4 v = *(const uint4*)&Wb[h * 128 + k0 + j];
            *(uint4*)&sW[h * LDW + k0 + j] = v;
        }
    }
    {   // stage 64 edge rows fp32 -> bf16 into padded LDS
        int e = t >> 2, q = t & 3;
        const float* ep = &edge_h[(size_t)(e0 + e) * 128 + q * 32];
        unsigned short* ap = &sA[e * LDW + q * 32];
        #pragma unroll
        for (int j = 0; j < 32; j += 8) {
            float4 x = *(const float4*)&ep[j];
            float4 y = *(const float4*)&ep[j + 4];
            uint4 p;
            p.x = (unsigned)f2bf(x.x) | ((unsigned)f2bf(x.y) << 16);
            p.y = (unsigned)f2bf(x.z) | ((unsigned)f2bf(x.w) << 16);
            p.z = (unsigned)f2bf(y.x) | ((unsigned)f2bf(y.y) << 16);
            p.w = (unsigned)f2bf(y.z) | ((unsigned)f2bf(y.w) << 16);
            *(uint4*)&ap[j] = p;
        }
    }
    if (t < 64) {
        sSrc[t]  = src[e0 + t];
        sDst[t]  = dst[e0 + t];
        sNorm[t] = nrm[e0 + t];
    }
    __syncthreads();

    int lane = t & 63;
    int wv   = t >> 6;        // wave 0..3 -> 32-col slab
    int ln15 = lane & 15;
    int quad = lane >> 4;

    f32x4 zero = {0.f, 0.f, 0.f, 0.f};
    f32x4 acc[4][2];
    #pragma unroll
    for (int mt = 0; mt < 4; ++mt)
        #pragma unroll
        for (int nt = 0; nt < 2; ++nt) acc[mt][nt] = zero;

    #pragma unroll
    for (int kk = 0; kk < 4; ++kk) {
        int ko = kk * 32 + quad * 8;           // A/B frag: row = lane&15, k = quad*8+j
        bf16x8 a[4], b[2];
        #pragma unroll
        for (int mt = 0; mt < 4; ++mt)
            a[mt] = *(const bf16x8*)&sA[(mt * 16 + ln15) * LDW + ko];
        #pragma unroll
        for (int nt = 0; nt < 2; ++nt)
            b[nt] = *(const bf16x8*)&sW[(wv * 32 + nt * 16 + ln15) * LDW + ko];
        #pragma unroll
        for (int mt = 0; mt < 4; ++mt)
            #pragma unroll
            for (int nt = 0; nt < 2; ++nt)
                acc[mt][nt] = __builtin_amdgcn_mfma_f32_16x16x32_bf16(
                    a[mt], b[nt], acc[mt][nt], 0, 0, 0);
    }

    // epilogue: C/D layout row = quad*4+r (edge), col = lane&15 (hid)
    // -> 16 lanes of a quad share one edge, cols contiguous: 64B gathers/atomics
    #pragma unroll
    for (int mt = 0; mt < 4; ++mt) {
        #pragma unroll
        for (int nt = 0; nt < 2; ++nt) {
            int n = wv * 32 + nt * 16 + ln15;
            #pragma unroll
            for (int r = 0; r < 4; ++r) {
                int m = mt * 16 + quad * 4 + r;
                float v = (acc[mt][nt][r] + proj[(size_t)sSrc[m] * 128 + n]) * sNorm[m];
                atomicAdd(&out[(size_t)sDst[m] * 128 + n], v);
            }
        }
    }
}

// ---------------------------------------------------------------- leaky relu
__global__ void act_kernel(float* __restrict__ out) {
    int i = blockIdx.x * 256 + threadIdx.x;
    if (i < NN * D / 4) {
        float4* p = (float4*)out;
        float4 v = p[i];
        v.x = v.x >= 0.f ? v.x : SLOPE * v.x;
        v.y = v.y >= 0.f ? v.y : SLOPE * v.y;
        v.z = v.z >= 0.f ? v.z : SLOPE * v.z;
        v.w = v.w >= 0.f ? v.w : SLOPE * v.w;
        p[i] = v;
    }
}

extern "C" void kernel_launch(void* const* d_in, const int* in_sizes, int n_in,
                              void* d_out, int out_size, void* d_ws, size_t ws_size,
                              hipStream_t stream) {
    const float* node_h = (const float*)d_in[0];
    const float* edge_h = (const float*)d_in[1];
    const float* nrm    = (const float*)d_in[2];
    const float* W      = (const float*)d_in[3];
    const int*   src    = (const int*)d_in[4];
    const int*   dst    = (const int*)d_in[5];
    float* out = (float*)d_out;

    float* proj = (float*)d_ws;                                  // 10000*128 f32 = 5.12 MB
    unsigned short* Wb = (unsigned short*)((char*)d_ws + (size_t)NN * D * sizeof(float)); // 32 KB

    hipMemsetAsync(d_out, 0, (size_t)out_size * sizeof(float), stream);
    wconv_kernel<<<64, 256, 0, stream>>>(W, Wb);
    proj_kernel<<<NN / 8, 256, 0, stream>>>(node_h, W, proj);
    edge_kernel<<<NE / 64, 256, 0, stream>>>(edge_h, nrm, src, dst, Wb, proj, out);
    act_kernel<<<(NN * D / 4 + 255) / 256, 256, 0, stream>>>(out);
}

// Round 2
// 609.039 us; speedup vs baseline: 1.1350x; 1.1350x over previous
//
#include <hip/hip_runtime.h>

#define NN 10000
#define NE 640000
#define D  128
#define SLOPE 0.22916666666666666f   // 11/48

// ---------------------------------------------------------------- CSR build
// counts pre-zeroed by hipMemsetAsync
__global__ void hist_kernel(const int* __restrict__ dst, int* __restrict__ cnt) {
    int e = blockIdx.x * 256 + threadIdx.x;
    if (e < NE) atomicAdd(&cnt[dst[e]], 1);
}

// exclusive prefix sum of cnt[NN] -> cur[NN] (single block, 1024 threads)
__global__ __launch_bounds__(1024) void scan_kernel(const int* __restrict__ cnt,
                                                    int* __restrict__ cur) {
    __shared__ int sums[1024];
    int t = threadIdx.x;
    int base = t * 10;                 // 1024*10 >= 10000
    int local[10];
    int s = 0;
    #pragma unroll
    for (int i = 0; i < 10; ++i) {
        int v = (base + i < NN) ? cnt[base + i] : 0;
        local[i] = s; s += v;
    }
    sums[t] = s;
    __syncthreads();
    for (int off = 1; off < 1024; off <<= 1) {
        int v = (t >= off) ? sums[t - off] : 0;
        __syncthreads();
        sums[t] += v;
        __syncthreads();
    }
    int prev = sums[t] - s;            // exclusive offset of this thread's chunk
    #pragma unroll
    for (int i = 0; i < 10; ++i)
        if (base + i < NN) cur[base + i] = prev + local[i];
}

// place edge ids; afterwards cur[d] == end offset of segment d
__global__ void scatter_kernel(const int* __restrict__ dst, int* __restrict__ cur,
                               int* __restrict__ order) {
    int e = blockIdx.x * 256 + threadIdx.x;
    if (e < NE) {
        int p = atomicAdd(&cur[dst[e]], 1);
        order[p] = e;
    }
}

// ---------------------------------------------------------------- per-dst aggregation
// agg[d][0..127]   = sum_e norm_e * node_h[src_e]   (t)
// agg[d][128..255] = sum_e norm_e * edge_h[e]       (s)
// one wave per dst; lane covers 4 floats; lanes 0-31 node half, 32-63 edge half
__global__ __launch_bounds__(256) void agg_kernel(
    const float* __restrict__ node_h, const float* __restrict__ edge_h,
    const float* __restrict__ nrm, const int* __restrict__ src,
    const int* __restrict__ order, const int* __restrict__ cur,
    float* __restrict__ agg) {
    int t = threadIdx.x;
    int d = blockIdx.x * 4 + (t >> 6);
    int lane = t & 63;
    int start = (d == 0) ? 0 : cur[d - 1];
    int end = cur[d];
    int half = lane >> 5;
    int c = (lane & 31) * 4;

    float4 acc = {0.f, 0.f, 0.f, 0.f};

    int j = start;
    int e0 = 0, s0 = 0, e1 = 0, s1 = 0;
    float w0 = 0.f, w1 = 0.f;
    if (j < end)     { e0 = order[j];     s0 = src[e0]; w0 = nrm[e0]; }
    if (j + 1 < end) { e1 = order[j + 1]; s1 = src[e1]; w1 = nrm[e1]; }

    while (j + 1 < end) {
        const float* p0 = half ? &edge_h[(size_t)e0 * D + c] : &node_h[(size_t)s0 * D + c];
        const float* p1 = half ? &edge_h[(size_t)e1 * D + c] : &node_h[(size_t)s1 * D + c];
        float4 v0 = *(const float4*)p0;
        float4 v1 = *(const float4*)p1;
        int jn = j + 2;
        int en0 = 0, sn0 = 0, en1 = 0, sn1 = 0;
        float wn0 = 0.f, wn1 = 0.f;
        if (jn < end)     { en0 = order[jn];     sn0 = src[en0]; wn0 = nrm[en0]; }
        if (jn + 1 < end) { en1 = order[jn + 1]; sn1 = src[en1]; wn1 = nrm[en1]; }
        acc.x += w0 * v0.x; acc.y += w0 * v0.y; acc.z += w0 * v0.z; acc.w += w0 * v0.w;
        acc.x += w1 * v1.x; acc.y += w1 * v1.y; acc.z += w1 * v1.z; acc.w += w1 * v1.w;
        e0 = en0; s0 = sn0; w0 = wn0;
        e1 = en1; s1 = sn1; w1 = wn1;
        j = jn;
    }
    if (j < end) {   // tail edge (meta already in e0/s0/w0)
        const float* p0 = half ? &edge_h[(size_t)e0 * D + c] : &node_h[(size_t)s0 * D + c];
        float4 v0 = *(const float4*)p0;
        acc.x += w0 * v0.x; acc.y += w0 * v0.y; acc.z += w0 * v0.z; acc.w += w0 * v0.w;
    }
    *(float4*)&agg[(size_t)d * 256 + half * 128 + c] = acc;
}

// ---------------------------------------------------------------- GEMM + LeakyReLU
// out[n][h] = act( sum_{k<256} W[h][k] * agg[n][k] )   (fp32 vector)
#define TN 32          // nodes per block
#define LDA 34         // sAT row stride (even -> aligned float2, conflict-free)
#define LDWT 136       // sWT row stride

__global__ __launch_bounds__(256) void gemm_kernel(
    const float* __restrict__ agg, const float* __restrict__ W,
    float* __restrict__ out) {
    __shared__ float sAT[256 * LDA];    // [k][n]  34.8 KB
    __shared__ float sWT[32 * LDWT];    // [kl][h] 17.4 KB
    int t = threadIdx.x;
    int n0 = blockIdx.x * TN;

    {   // stage agg transposed: thread: n = t>>3, kg = (t&7)*32
        int n = t >> 3, kg = (t & 7) * 32;
        bool ok = (n0 + n) < NN;
        const float* srcp = &agg[(size_t)(n0 + n) * 256 + kg];
        #pragma unroll
        for (int j = 0; j < 32; j += 4) {
            float4 v = ok ? *(const float4*)&srcp[j] : float4{0.f, 0.f, 0.f, 0.f};
            sAT[(kg + j + 0) * LDA + n] = v.x;
            sAT[(kg + j + 1) * LDA + n] = v.y;
            sAT[(kg + j + 2) * LDA + n] = v.z;
            sAT[(kg + j + 3) * LDA + n] = v.w;
        }
    }

    int n2 = (t >> 4) * 2;         // node pair
    int h0 = (t & 15) * 4;         // cols h0..h0+3 and 64+h0..64+h0+3
    float acc[2][8];
    #pragma unroll
    for (int i = 0; i < 2; ++i)
        #pragma unroll
        for (int j = 0; j < 8; ++j) acc[i][j] = 0.f;

    for (int kc = 0; kc < 256; kc += 32) {
        __syncthreads();           // protect prev sWT reads; covers sAT staging on iter 0 (paired with next)
        {   // stage W chunk transposed: thread: h = t>>1, kl0 = (t&1)*16
            int h = t >> 1, kl0 = (t & 1) * 16;
            const float* wp = &W[(size_t)h * 256 + kc + kl0];
            #pragma unroll
            for (int j = 0; j < 16; j += 4) {
                float4 v = *(const float4*)&wp[j];
                sWT[(kl0 + j + 0) * LDWT + h] = v.x;
                sWT[(kl0 + j + 1) * LDWT + h] = v.y;
                sWT[(kl0 + j + 2) * LDWT + h] = v.z;
                sWT[(kl0 + j + 3) * LDWT + h] = v.w;
            }
        }
        __syncthreads();
        #pragma unroll
        for (int kl = 0; kl < 32; ++kl) {
            int k = kc + kl;
            float2 a01 = *(const float2*)&sAT[k * LDA + n2];
            const float* wr = &sWT[kl * LDWT];
            float4 wA = *(const float4*)&wr[h0];
            float4 wB = *(const float4*)&wr[64 + h0];
            acc[0][0] += a01.x * wA.x; acc[0][1] += a01.x * wA.y;
            acc[0][2] += a01.x * wA.z; acc[0][3] += a01.x * wA.w;
            acc[0][4] += a01.x * wB.x; acc[0][5] += a01.x * wB.y;
            acc[0][6] += a01.x * wB.z; acc[0][7] += a01.x * wB.w;
            acc[1][0] += a01.y * wA.x; acc[1][1] += a01.y * wA.y;
            acc[1][2] += a01.y * wA.z; acc[1][3] += a01.y * wA.w;
            acc[1][4] += a01.y * wB.x; acc[1][5] += a01.y * wB.y;
            acc[1][6] += a01.y * wB.z; acc[1][7] += a01.y * wB.w;
        }
    }

    #pragma unroll
    for (int i = 0; i < 2; ++i) {
        int n = n0 + n2 + i;
        if (n < NN) {
            float4 o1, o2;
            o1.x = acc[i][0] >= 0.f ? acc[i][0] : SLOPE * acc[i][0];
            o1.y = acc[i][1] >= 0.f ? acc[i][1] : SLOPE * acc[i][1];
            o1.z = acc[i][2] >= 0.f ? acc[i][2] : SLOPE * acc[i][2];
            o1.w = acc[i][3] >= 0.f ? acc[i][3] : SLOPE * acc[i][3];
            o2.x = acc[i][4] >= 0.f ? acc[i][4] : SLOPE * acc[i][4];
            o2.y = acc[i][5] >= 0.f ? acc[i][5] : SLOPE * acc[i][5];
            o2.z = acc[i][6] >= 0.f ? acc[i][6] : SLOPE * acc[i][6];
            o2.w = acc[i][7] >= 0.f ? acc[i][7] : SLOPE * acc[i][7];
            *(float4*)&out[(size_t)n * D + h0] = o1;
            *(float4*)&out[(size_t)n * D + 64 + h0] = o2;
        }
    }
}

extern "C" void kernel_launch(void* const* d_in, const int* in_sizes, int n_in,
                              void* d_out, int out_size, void* d_ws, size_t ws_size,
                              hipStream_t stream) {
    const float* node_h = (const float*)d_in[0];
    const float* edge_h = (const float*)d_in[1];
    const float* nrm    = (const float*)d_in[2];
    const float* W      = (const float*)d_in[3];
    const int*   src    = (const int*)d_in[4];
    const int*   dst    = (const int*)d_in[5];
    float* out = (float*)d_out;

    // workspace layout (~12.9 MB)
    float* agg  = (float*)d_ws;                                    // NN*256 f32 = 10.24 MB
    int*  order = (int*)((char*)d_ws + (size_t)NN * 256 * 4);      // NE ints   = 2.56 MB
    int*  cnt   = order + NE;                                      // NN ints
    int*  cur   = cnt + NN;                                        // NN ints

    hipMemsetAsync(cnt, 0, (size_t)NN * sizeof(int), stream);
    hist_kernel<<<NE / 256, 256, 0, stream>>>(dst, cnt);
    scan_kernel<<<1, 1024, 0, stream>>>(cnt, cur);
    scatter_kernel<<<NE / 256, 256, 0, stream>>>(dst, cur, order);
    agg_kernel<<<NN / 4, 256, 0, stream>>>(node_h, edge_h, nrm, src, order, cur, agg);
    gemm_kernel<<<(NN + TN - 1) / TN, 256, 0, stream>>>(agg, W, out);
}

// Round 3
// 581.187 us; speedup vs baseline: 1.1894x; 1.0479x over previous
//
#include <hip/hip_runtime.h>

#define NN 10000
#define NE 640000
#define D  128
#define SLOPE 0.22916666666666666f   // 11/48

// ---------------------------------------------------------------- W transpose
// WT[k][h] = W[h][k], k in [0,256), h in [0,128). Done once, 131 KB.
__global__ void wtrans_kernel(const float* __restrict__ W, float* __restrict__ WT) {
    int i = blockIdx.x * 256 + threadIdx.x;     // 32768
    int h = i >> 8, k = i & 255;                // coalesced read over k
    WT[k * 128 + h] = W[i];
}

// ---------------------------------------------------------------- CSR build
__global__ void hist_kernel(const int* __restrict__ dst, int* __restrict__ cnt) {
    int e = blockIdx.x * 256 + threadIdx.x;
    if (e < NE) atomicAdd(&cnt[dst[e]], 1);
}

// exclusive prefix sum of cnt[NN] -> cur[NN] (single block, 1024 threads)
__global__ __launch_bounds__(1024) void scan_kernel(const int* __restrict__ cnt,
                                                    int* __restrict__ cur) {
    __shared__ int sums[1024];
    int t = threadIdx.x;
    int base = t * 10;                 // 1024*10 >= 10000
    int local[10];
    int s = 0;
    #pragma unroll
    for (int i = 0; i < 10; ++i) {
        int v = (base + i < NN) ? cnt[base + i] : 0;
        local[i] = s; s += v;
    }
    sums[t] = s;
    __syncthreads();
    for (int off = 1; off < 1024; off <<= 1) {
        int v = (t >= off) ? sums[t - off] : 0;
        __syncthreads();
        sums[t] += v;
        __syncthreads();
    }
    int prev = sums[t] - s;            // exclusive offset of this thread's chunk
    #pragma unroll
    for (int i = 0; i < 10; ++i)
        if (base + i < NN) cur[base + i] = prev + local[i];
}

// place sorted meta; afterwards cur[d] == end offset of segment d
__global__ void scatter_kernel(const int* __restrict__ dst, const int* __restrict__ src,
                               const float* __restrict__ nrm, int* __restrict__ cur,
                               int2* __restrict__ meta, float* __restrict__ nrmS) {
    int e = blockIdx.x * 256 + threadIdx.x;
    if (e < NE) {
        int p = atomicAdd(&cur[dst[e]], 1);
        meta[p] = make_int2(e, src[e]);
        nrmS[p] = nrm[e];
    }
}

// ---------------------------------------------------------------- per-dst aggregation
// agg[d][0..127]   = sum_e norm_e * node_h[src_e]
// agg[d][128..255] = sum_e norm_e * edge_h[e]
// one wave per dst; lanes 0-31 node half, 32-63 edge half; 4 floats/lane
__global__ __launch_bounds__(256) void agg_kernel(
    const float* __restrict__ node_h, const float* __restrict__ edge_h,
    const int2* __restrict__ meta, const float* __restrict__ nrmS,
    const int* __restrict__ cur, float* __restrict__ agg) {
    int t = threadIdx.x;
    int d = blockIdx.x * 4 + (t >> 6);
    int lane = t & 63;
    int start = (d == 0) ? 0 : cur[d - 1];
    int end = cur[d];
    int half = lane >> 5;
    int c = (lane & 31) * 4;

    float4 acc = {0.f, 0.f, 0.f, 0.f};

    if (start < end) {
        int2 m[4]; float w[4];
        #pragma unroll
        for (int i = 0; i < 4; ++i) {     // first meta group (linear, broadcast)
            int idx = (start + i < end) ? start + i : end - 1;
            m[i] = meta[idx];
            w[i] = (start + i < end) ? nrmS[idx] : 0.f;
        }
        for (int j = start; j < end; ) {
            int2 cm[4]; float cw[4];
            #pragma unroll
            for (int i = 0; i < 4; ++i) { cm[i] = m[i]; cw[i] = w[i]; }
            int jn = j + 4;
            if (jn < end) {               // prefetch next meta group
                #pragma unroll
                for (int i = 0; i < 4; ++i) {
                    int idx = (jn + i < end) ? jn + i : end - 1;
                    m[i] = meta[idx];
                    w[i] = (jn + i < end) ? nrmS[idx] : 0.f;
                }
            }
            #pragma unroll
            for (int i = 0; i < 4; ++i) {
                const float* p = half ? &edge_h[(size_t)cm[i].x * D + c]
                                      : &node_h[(size_t)cm[i].y * D + c];
                float4 v = *(const float4*)p;
                acc.x += cw[i] * v.x; acc.y += cw[i] * v.y;
                acc.z += cw[i] * v.z; acc.w += cw[i] * v.w;
            }
            j = jn;
        }
    }
    *(float4*)&agg[(size_t)d * 256 + half * 128 + c] = acc;
}

// ---------------------------------------------------------------- GEMM + LeakyReLU
// out[n][h] = act( sum_{k<256} WT[k][h] * agg[n][k] )  (fp32)
#define TN  16     // nodes per block -> 625 blocks
#define LDA 18     // sAT row stride (float2-aligned, pad vs 16)

__global__ __launch_bounds__(256) void gemm_kernel(
    const float* __restrict__ agg, const float* __restrict__ WT,
    float* __restrict__ out) {
    __shared__ float sAT[256 * LDA];    // [k][n]  18.4 KB
    __shared__ float sW[32 * 128];      // [kl][h] 16.4 KB
    int t = threadIdx.x;
    int n0 = blockIdx.x * TN;

    {   // stage agg transposed: n = t&15, kg = (t>>4)*16  (4-way bank alias on writes)
        int n = t & 15, kg = (t >> 4) * 16;
        bool ok = (n0 + n) < NN;
        const float* sp = &agg[(size_t)(n0 + n) * 256 + kg];
        #pragma unroll
        for (int j = 0; j < 16; j += 4) {
            float4 v = ok ? *(const float4*)&sp[j] : float4{0.f, 0.f, 0.f, 0.f};
            sAT[(kg + j + 0) * LDA + n] = v.x;
            sAT[(kg + j + 1) * LDA + n] = v.y;
            sAT[(kg + j + 2) * LDA + n] = v.z;
            sAT[(kg + j + 3) * LDA + n] = v.w;
        }
    }

    int n2 = (t >> 5) * 2;       // node pair 0..14
    int h0 = (t & 31) * 4;       // all 128 cols
    float acc[2][4] = {{0.f,0.f,0.f,0.f},{0.f,0.f,0.f,0.f}};

    for (int kc = 0; kc < 256; kc += 32) {
        __syncthreads();         // protect prev sW reads; covers sAT staging on iter 0
        {   // stage 32x128 chunk of WT, fully linear/coalesced
            const float4* wp = (const float4*)&WT[kc * 128];
            float4* dp = (float4*)sW;
            dp[t]       = wp[t];
            dp[t + 256] = wp[t + 256];
            dp[t + 512] = wp[t + 512];
            dp[t + 768] = wp[t + 768];
        }
        __syncthreads();
        #pragma unroll
        for (int kl = 0; kl < 32; ++kl) {
            int k = kc + kl;
            float2 a = *(const float2*)&sAT[k * LDA + n2];       // broadcast per 32 lanes
            float4 w = *(const float4*)&sW[kl * 128 + h0];       // contiguous b128
            acc[0][0] += a.x * w.x; acc[0][1] += a.x * w.y;
            acc[0][2] += a.x * w.z; acc[0][3] += a.x * w.w;
            acc[1][0] += a.y * w.x; acc[1][1] += a.y * w.y;
            acc[1][2] += a.y * w.z; acc[1][3] += a.y * w.w;
        }
    }

    #pragma unroll
    for (int i = 0; i < 2; ++i) {
        int n = n0 + n2 + i;
        if (n < NN) {
            float4 o;
            o.x = acc[i][0] >= 0.f ? acc[i][0] : SLOPE * acc[i][0];
            o.y = acc[i][1] >= 0.f ? acc[i][1] : SLOPE * acc[i][1];
            o.z = acc[i][2] >= 0.f ? acc[i][2] : SLOPE * acc[i][2];
            o.w = acc[i][3] >= 0.f ? acc[i][3] : SLOPE * acc[i][3];
            *(float4*)&out[(size_t)n * D + h0] = o;
        }
    }
}

extern "C" void kernel_launch(void* const* d_in, const int* in_sizes, int n_in,
                              void* d_out, int out_size, void* d_ws, size_t ws_size,
                              hipStream_t stream) {
    const float* node_h = (const float*)d_in[0];
    const float* edge_h = (const float*)d_in[1];
    const float* nrm    = (const float*)d_in[2];
    const float* W      = (const float*)d_in[3];
    const int*   src    = (const int*)d_in[4];
    const int*   dst    = (const int*)d_in[5];
    float* out = (float*)d_out;

    // workspace layout (~18.2 MB)
    char* p = (char*)d_ws;
    float* agg  = (float*)p;              p += (size_t)NN * 256 * 4;   // 10.24 MB
    int2*  meta = (int2*)p;               p += (size_t)NE * 8;         //  5.12 MB
    float* nrmS = (float*)p;              p += (size_t)NE * 4;         //  2.56 MB
    float* WT   = (float*)p;              p += (size_t)256 * 128 * 4;  //  131 KB
    int*   cnt  = (int*)p;                p += (size_t)NN * 4;
    int*   cur  = (int*)p;

    hipMemsetAsync(cnt, 0, (size_t)NN * sizeof(int), stream);
    wtrans_kernel<<<128, 256, 0, stream>>>(W, WT);
    hist_kernel<<<NE / 256, 256, 0, stream>>>(dst, cnt);
    scan_kernel<<<1, 1024, 0, stream>>>(cnt, cur);
    scatter_kernel<<<NE / 256, 256, 0, stream>>>(dst, src, nrm, cur, meta, nrmS);
    agg_kernel<<<NN / 4, 256, 0, stream>>>(node_h, edge_h, meta, nrmS, cur, agg);
    gemm_kernel<<<(NN + TN - 1) / TN, 256, 0, stream>>>(agg, WT, out);
}